// Round 2
// baseline (4241.419 us; speedup 1.0000x reference)
//
#include <hip/hip_runtime.h>
#include <stdint.h>

// ---------------------------------------------------------------------------
// 3-layer packed-sequence LSTM, B=64 T=2048 D=40 H=164, FC->7. fp32 in/out.
//
// Staircase-pipelined launch chain (NO inter-block sync, cannot hang):
//   for i in 0..17:
//     kgemm(i): input projections gx_l(chunk i-l) via mfma_f32_16x16x32_f16
//     krec (i): recurrence blocks (l=0,chunk i), (l=1,chunk i-1), (l=2,chunk i-2)
//   Dependencies satisfied purely by kernel launch boundaries; the three
//   layers overlap in time (chunk-granular software pipeline).
//
// Recurrent step (krec, 704 thr = 11 waves, one gate-row per lane):
//   h (164 f16 padded to 168 = 84 dwords) lives in LDS; each wave loads it
//   as 2 lane-distributed VGPRs (2 ds_read_b32), then broadcasts dword k via
//   v_readlane -> SGPR -> v_dot2_f32_f16 (SGPR operand legal in VOP3P).
//   This avoids the ~231 ds_read_b128/step LDS-broadcast cost (~2800 cy);
//   dot phase is VALU-bound at ~1000 cy/step.
// ---------------------------------------------------------------------------

#define TT 2048
#define BB 64
#define GG 656   // 4*H
#define HH 164
#define CC 128   // chunk timesteps
#define NCH (TT/CC)   // 16

typedef _Float16 half2v __attribute__((ext_vector_type(2)));
typedef _Float16 half8  __attribute__((ext_vector_type(8)));
typedef float    f32x4  __attribute__((ext_vector_type(4)));

// ---- workspace layout (bytes) ----
#define SZ_W16_B   (3*GG*192*2)                 // f16 [3][656][192]
#define OFF_WIH_B  0
#define OFF_WHH_B  (SZ_W16_B)
#define OFF_GX_B   (2*SZ_W16_B)
#define SZ_GX_B    ((size_t)3*BB*CC*GG*2)       // f16 [3][64][128][656]
#define OFF_HR_B   (OFF_GX_B + SZ_GX_B)
#define SZ_HR_B    ((size_t)2*2*BB*CC*96*4)     // dwords [2 layers][2 slots][64][128][96]
#define OFF_SC_B   (OFF_HR_B + SZ_HR_B)
#define SZ_SC_B    (3*BB*HH*4)                  // f32 c-state
#define OFF_SH_B   (OFF_SC_B + SZ_SC_B)
#define SZ_SH_B    (3*BB*96*4)                  // dword h-state (f16 pairs)
#define WS_TOTAL_B (OFF_SH_B + SZ_SH_B)         // ~46.5 MB

__device__ __forceinline__ float dot2(uint32_t w, uint32_t h, float acc) {
#if __has_builtin(__builtin_amdgcn_fdot2)
  return __builtin_amdgcn_fdot2(__builtin_bit_cast(half2v, w),
                                __builtin_bit_cast(half2v, h), acc, false);
#else
  half2v a = __builtin_bit_cast(half2v, w);
  half2v b = __builtin_bit_cast(half2v, h);
  return acc + (float)a[0]*(float)b[0] + (float)a[1]*(float)b[1];
#endif
}

__device__ __forceinline__ float sigmf(float x) { return 1.0f/(1.0f + __expf(-x)); }
__device__ __forceinline__ float tanhf_(float x) { return 2.0f/(1.0f + __expf(-2.0f*x)) - 1.0f; }

// ---------------------------------------------------------------------------
// weight prep: fp32 -> f16, pad K to 192 halves (zeros), row-major [3][656][192]
// ---------------------------------------------------------------------------
__global__ void kprep_w(const float* wih0, const float* whh0,
                        const float* wih1, const float* whh1,
                        const float* wih2, const float* whh2,
                        _Float16* wih16, _Float16* whh16) {
  int i = threadIdx.x + blockIdx.x * blockDim.x;
  if (i >= 3*GG*192) return;
  int l = i / (GG*192);
  int r = i - l*(GG*192);
  int j = r / 192;
  int k = r - j*192;
  float vi = 0.f, vh = 0.f;
  if (l == 0) {
    if (k < 40) vi = wih0[j*40 + k];
    if (k < HH) vh = whh0[j*HH + k];
  } else if (l == 1) {
    if (k < HH) vi = wih1[j*HH + k];
    if (k < HH) vh = whh1[j*HH + k];
  } else {
    if (k < HH) vi = wih2[j*HH + k];
    if (k < HH) vh = whh2[j*HH + k];
  }
  wih16[i] = (_Float16)vi;
  whh16[i] = (_Float16)vh;
}

// ---------------------------------------------------------------------------
// input-projection GEMM for one chunk: gx[l][b][row 0..127][656] f16
//   layer 0: A = x (fp32, converted on the fly, K padded 40->64)
//   layer 1/2: A = h ring of previous layer (f16 pairs, K padded 164->192)
// grid 192 (= 3 layers x 64 batches), 256 threads (4 waves)
// ---------------------------------------------------------------------------
__launch_bounds__(256, 4)
__global__ void kgemm(int step, const int* lengths, const float* x,
                      const uint32_t* wihw, const uint32_t* hring,
                      uint16_t* gx) {
  const int l  = blockIdx.x >> 6;
  const int b  = blockIdx.x & 63;
  const int ch = step - l;
  if (ch < 0 || ch >= NCH) return;
  int len = lengths[b];
  if (len < 1) len = 1; if (len > TT) len = TT;
  if (ch*CC >= len) return;                    // whole chunk past this sequence
  const int tid  = threadIdx.x;
  const int lane = tid & 63, wv = tid >> 6;
  const int quad = lane >> 4, n15 = lane & 15;
  const int Kt = (l == 0) ? 2 : 6;
  uint16_t* gxo = gx + (size_t)(l*BB + b)*CC*GG;
  const uint32_t* hbs = (l > 0)
      ? hring + ((size_t)((l-1)*2 + (ch & 1))*BB + b)*CC*96 : (const uint32_t*)0;

  __shared__ __align__(16) uint32_t smem[3200];  // 32 rows x 100 dwords

  for (int st = 0; st < 4; ++st) {
    // ---- stage A-tile (32 timesteps x K halves) ----
    if (l == 0) {
      for (int idx = tid; idx < 32*32; idx += 256) {
        int row = idx >> 5, dw = idx & 31;
        int t = ch*CC + st*32 + row;
        uint32_t v = 0;
        if (dw < 20) {
          const float* xs = x + ((size_t)b*TT + t)*40 + dw*2;
          half2v p; p[0] = (_Float16)xs[0]; p[1] = (_Float16)xs[1];
          v = __builtin_bit_cast(uint32_t, p);
        }
        smem[row*100 + dw] = v;
      }
    } else {
      for (int idx = tid; idx < 32*96; idx += 256) {
        int row = idx / 96, dw = idx - row*96;
        smem[row*100 + dw] = hbs[(size_t)(st*32 + row)*96 + dw];
      }
    }
    __syncthreads();

    // ---- MFMA: [32 x K] @ W^T -> [32 x 656]; 4 waves over 41 N-tiles ----
    const half8* asrc = (const half8*)smem;     // row stride 25 half8
    for (int nt = wv; nt < 41; nt += 4) {
      int wrow = nt*16 + n15;
      const half8* bsrc = (const half8*)(wihw + (size_t)(l*GG + wrow)*96);
      f32x4 a0 = {0.f,0.f,0.f,0.f};
      f32x4 a1 = {0.f,0.f,0.f,0.f};
      for (int kk = 0; kk < Kt; ++kk) {
        half8 bf  = bsrc[kk*4 + quad];
        half8 af0 = asrc[ n15      *25 + kk*4 + quad];
        half8 af1 = asrc[(n15 + 16)*25 + kk*4 + quad];
        a0 = __builtin_amdgcn_mfma_f32_16x16x32_f16(af0, bf, a0, 0, 0, 0);
        a1 = __builtin_amdgcn_mfma_f32_16x16x32_f16(af1, bf, a1, 0, 0, 0);
      }
      #pragma unroll
      for (int r = 0; r < 4; ++r) {
        int row0 = st*32 + quad*4 + r;          // C/D: col=lane&15, row=quad*4+reg
        _Float16 h0 = (_Float16)a0[r];
        _Float16 h1 = (_Float16)a1[r];
        gxo[(size_t)row0*GG + wrow]        = __builtin_bit_cast(uint16_t, h0);
        gxo[(size_t)(row0 + 16)*GG + wrow] = __builtin_bit_cast(uint16_t, h1);
      }
    }
    __syncthreads();
  }
}

// ---------------------------------------------------------------------------
// recurrence for one chunk of one (layer, batch): 704 threads, 1 gate-row/lane
// grid 192 (= 3 layers x 64 batches)
// ---------------------------------------------------------------------------
__launch_bounds__(704, 3)
__global__ void krec(int step, const int* lengths,
                     const float* b0, const float* b1, const float* b2,
                     const uint32_t* whhw, const uint16_t* gx,
                     uint32_t* hring, float* state_c, uint32_t* state_h) {
  const int l  = blockIdx.x >> 6;
  const int b  = blockIdx.x & 63;
  const int ch = step - l;
  if (ch < 0 || ch >= NCH) return;
  int len = lengths[b];
  if (len < 1) len = 1; if (len > TT) len = TT;
  const int t0 = ch*CC;
  if (t0 >= len) return;                        // frozen; state already final
  int t1 = t0 + CC; if (t1 > len) t1 = len;

  const int tid = threadIdx.x;
  const int r   = (tid < GG) ? tid : (GG - 1);

  __shared__ __align__(16) uint32_t hdw[96];    // h as f16 pairs (dwords 82..95 = 0)
  __shared__ float gates[GG];

  // W_hh row r: 84 packed-f16-pair dwords (K padded 164->168; rest unused)
  uint4 w4[21];
  {
    const uint4* ws4 = (const uint4*)(whhw + (size_t)(l*GG + r)*96);
    #pragma unroll
    for (int c = 0; c < 21; ++c) w4[c] = ws4[c];
  }
  const uint32_t* wr = (const uint32_t*)w4;
  const float* bp = (l == 0) ? b0 : ((l == 1) ? b1 : b2);
  const float bias = bp[r];

  float cst = 0.f;
  if (ch == 0) {
    if (tid < 96) hdw[tid] = 0u;
  } else {
    if (tid < 96) hdw[tid] = state_h[(l*BB + b)*96 + tid];
    if (tid < HH) cst = state_c[(l*BB + b)*HH + tid];
  }
  __syncthreads();

  const uint16_t* gxb = gx + (size_t)(l*BB + b)*CC*GG;
  uint32_t* hrb = (l < 2)
      ? hring + ((size_t)(l*2 + (ch & 1))*BB + b)*CC*96 : (uint32_t*)0;

  uint16_t gx16 = gxb[(size_t)0*GG + r];        // row 0 of chunk

  for (int t = t0; t < t1; ++t) {
    uint32_t hd0 = hdw[tid & 63];               // lane i holds h-dword i
    uint32_t hd1 = hdw[64 + (tid & 31)];        // lane i holds h-dword 64+i (i<32)

    // publish h(t-1) to ring (values already in hd0/hd1)
    if (l < 2 && t > t0) {
      int row = t - 1 - t0;
      if (tid < 64)       hrb[(size_t)row*96 + tid] = hd0;
      else if (tid < 96)  hrb[(size_t)row*96 + tid] = hd1;
    }

    // gate pre-activation: bias + gx + W_hh . h   (readlane SGPR broadcast)
    float acc0 = bias + (float)__builtin_bit_cast(_Float16, gx16);
    float acc1 = 0.f;
    #pragma unroll
    for (int k = 0; k < 64; k += 2) {
      acc0 = dot2(wr[k],   (uint32_t)__builtin_amdgcn_readlane((int)hd0, k),   acc0);
      acc1 = dot2(wr[k+1], (uint32_t)__builtin_amdgcn_readlane((int)hd0, k+1), acc1);
    }
    #pragma unroll
    for (int k = 0; k < 20; k += 2) {
      acc0 = dot2(wr[64+k], (uint32_t)__builtin_amdgcn_readlane((int)hd1, k),   acc0);
      acc1 = dot2(wr[65+k], (uint32_t)__builtin_amdgcn_readlane((int)hd1, k+1), acc1);
    }
    float acc = acc0 + acc1;
    if (tid < GG) gates[tid] = acc;

    // prefetch next gx
    if (t + 1 < t1) gx16 = gxb[(size_t)(t + 1 - t0)*GG + r];

    __syncthreads();                            // gates visible

    if (tid < HH) {                             // cell update, gate order i,f,g,o
      float gi = gates[tid];
      float gf = gates[tid +   HH];
      float gg = gates[tid + 2*HH];
      float go = gates[tid + 3*HH];
      cst = sigmf(gf)*cst + sigmf(gi)*tanhf_(gg);
      float h = sigmf(go)*tanhf_(cst);
      _Float16 h16 = (_Float16)h;
      ((uint16_t*)hdw)[tid] = __builtin_bit_cast(uint16_t, h16);
    }
    __syncthreads();                            // new h visible
  }

  // final publish of h(t1-1) + persist state
  {
    uint32_t v = (tid < 96) ? hdw[tid] : 0u;
    if (l < 2 && tid < 96) hrb[(size_t)(t1 - 1 - t0)*96 + tid] = v;
    if (tid < 96) state_h[(l*BB + b)*96 + tid] = v;
    if (tid < HH) state_c[(l*BB + b)*HH + tid] = cst;
  }
}

// ---------------------------------------------------------------------------
// FC epilogue on layer-2 final hidden state
// ---------------------------------------------------------------------------
__global__ void kfc(const float* fcw, const float* fcb,
                    const uint32_t* state_h, float* out) {
  int b = blockIdx.x, o = threadIdx.x;
  if (o >= 7) return;
  const uint16_t* h16 = (const uint16_t*)(state_h + (size_t)(2*BB + b)*96);
  float s = fcb[o];
  for (int m = 0; m < HH; ++m) {
    _Float16 hv = __builtin_bit_cast(_Float16, h16[m]);
    s += fcw[o*HH + m] * (float)hv;
  }
  out[b*7 + o] = s;
}

// ---------------------------------------------------------------------------
extern "C" void kernel_launch(void* const* d_in, const int* in_sizes, int n_in,
                              void* d_out, int out_size, void* d_ws, size_t ws_size,
                              hipStream_t stream) {
  const float* x      = (const float*)d_in[0];
  const int*  lengths = (const int*)  d_in[1];
  const float* wih0   = (const float*)d_in[2];
  const float* whh0   = (const float*)d_in[3];
  const float* b0     = (const float*)d_in[4];
  const float* wih1   = (const float*)d_in[5];
  const float* whh1   = (const float*)d_in[6];
  const float* b1     = (const float*)d_in[7];
  const float* wih2   = (const float*)d_in[8];
  const float* whh2   = (const float*)d_in[9];
  const float* b2     = (const float*)d_in[10];
  const float* fcw    = (const float*)d_in[11];
  const float* fcb    = (const float*)d_in[12];

  if (ws_size < (size_t)WS_TOTAL_B) return;     // loud, clean failure

  char* ws = (char*)d_ws;
  _Float16* wih16 = (_Float16*)(ws + OFF_WIH_B);
  _Float16* whh16 = (_Float16*)(ws + OFF_WHH_B);
  uint16_t* gxw   = (uint16_t*)(ws + OFF_GX_B);
  uint32_t* hrw   = (uint32_t*)(ws + OFF_HR_B);
  float*    scw   = (float*)   (ws + OFF_SC_B);
  uint32_t* shw   = (uint32_t*)(ws + OFF_SH_B);

  hipLaunchKernelGGL(kprep_w, dim3((3*GG*192 + 255)/256), dim3(256), 0, stream,
                     wih0, whh0, wih1, whh1, wih2, whh2, wih16, whh16);

  for (int i = 0; i < NCH + 2; ++i) {
    hipLaunchKernelGGL(kgemm, dim3(192), dim3(256), 0, stream,
                       i, lengths, x, (const uint32_t*)wih16, hrw, gxw);
    hipLaunchKernelGGL(krec, dim3(192), dim3(704), 0, stream,
                       i, lengths, b0, b1, b2, (const uint32_t*)whh16,
                       (const uint16_t*)gxw, hrw, scw, shw);
  }

  hipLaunchKernelGGL(kfc, dim3(64), dim3(64), 0, stream,
                     fcw, fcb, shw, (float*)d_out);
}